// Round 16
// baseline (6305.715 us; speedup 1.0000x reference)
//
#include <hip/hip_runtime.h>
#include <cstdint>
#include <cstddef>

typedef __attribute__((ext_vector_type(8))) short short8;
typedef __attribute__((ext_vector_type(4))) short short4v;
typedef __attribute__((ext_vector_type(4))) float f32x4;
typedef __attribute__((ext_vector_type(4))) int int4v;
typedef __attribute__((ext_vector_type(2))) int int2v;

static constexpr int B_ = 64, T_ = 256, D_ = 1024, NH = 1024, NG = 4096;
static constexpr int NROLE = 64;         // recurrence roles (16 units each)
static constexpr int NWRK  = 448;        // expected gemm workers
// LDS: recurrence Us(i8) 64K + zsm f32 64*64 = 16K = 80K exactly (2 blocks/CU)
static constexpr int LDS_BYTES = 65536 + 16384;
static constexpr uint64_t DLY_TICKS = 25;

__device__ __forceinline__ short f2bs(float f) {
  union { float f; uint32_t u; } cv; cv.f = f;
  uint32_t u = cv.u;
  uint32_t r = (u + 0x7fffu + ((u >> 16) & 1u)) >> 16;  // RNE
  return (short)(uint16_t)r;
}
__device__ __forceinline__ float bs2f(short s) {
  union { uint32_t u; float f; } cv; cv.u = ((uint32_t)(uint16_t)s) << 16; return cv.f;
}
__device__ __forceinline__ float fsigm(float x) {
  return __builtin_amdgcn_rcpf(1.f + __expf(-x));
}
__device__ __forceinline__ float ftanh(float x) {
  return 1.f - 2.f * __builtin_amdgcn_rcpf(__expf(2.f * x) + 1.f);
}
__device__ __forceinline__ uint64_t rtclock() {
  uint64_t v;
  asm volatile("s_memrealtime %0\n\ts_waitcnt lgkmcnt(0)" : "=s"(v));
  return v;
}

#define WAITV(N) do { asm volatile("s_waitcnt vmcnt(" #N ")" ::: "memory"); \
                      __builtin_amdgcn_sched_barrier(0); } while (0)

// one tagged dwordx4 (4 u32 = 8 i8 payload = one A-frag), fast(L2) / slow(MALL)
#define HLF(B0, VO) \
  asm volatile("global_load_dwordx4 %0, %1, %2 sc0" \
               : "=&v"(B0) : "v"(VO), "s"(hpv) : "memory")
#define HLS(B0, VO) \
  asm volatile("global_load_dwordx4 %0, %1, %2 sc0 sc1" \
               : "=&v"(B0) : "v"(VO), "s"(hpv) : "memory")

#define ISSUE_F(BUF, BASE) { _Pragma("unroll") \
  for (int K = 0; K < 8; ++K) HLF(BUF[K], voff0 + (BASE) + K * 4096); }
#define ISSUE_S(BUF, BASE) { _Pragma("unroll") \
  for (int K = 0; K < 8; ++K) HLS(BUF[K], voff0 + (BASE) + K * 4096); }

#define CHECKBUF(BUF) { _Pragma("unroll") \
  for (int i = 0; i < 8; ++i) { \
    bad |= ((uint32_t)BUF[i][0] ^ tgw); bad |= ((uint32_t)BUF[i][1] ^ tgw); \
    bad |= ((uint32_t)BUF[i][2] ^ tgw); bad |= ((uint32_t)BUF[i][3] ^ tgw); \
  } bad &= 0xFFFF0000u; }

// i8 MFMA over one buf (8 ksteps); A from tagged words (strip hi16), B from LDS
#define MFMA_SUB(BUF, KB) { _Pragma("unroll") \
  for (int K = 0; K < 8; ++K) { \
    int2v ad; \
    ad[0] = (BUF[K][0] & 0xFFFF) | ((BUF[K][1] & 0xFFFF) << 16); \
    ad[1] = (BUF[K][2] & 0xFFFF) | ((BUF[K][3] & 0xFFFF) << 16); \
    const long long a64 = __builtin_bit_cast(long long, ad); \
    const int ksAbs = kh * 16 + (KB) + K; \
    _Pragma("unroll") \
    for (int nt = 0; nt < 4; ++nt) { \
      const int boff = ((ksAbs * 4 + kg) * 64 + nt * 16 + fr) * 8; \
      const long long b64 = *reinterpret_cast<const long long*>(Us + boff); \
      acc[nt] = __builtin_amdgcn_mfma_i32_16x16x32_i8(a64, b64, acc[nt], 0, 0, 0); \
    } \
  } }

// ---------------------------------------------------------------------------
// MEGA kernel, 512 blocks x 512 thr (2/CU machine-wide):
//  - 64 roles (claimed by XCD0-affine blocks via XCC_ID ticket; workers rescue
//    leftovers after their tiles -> hang-free, placement only affects speed):
//    persistent recurrence, 16 units/role, U as i8 (per-col scale) in 64KB LDS,
//    h as (tag16|2xi8) u32 fragment-major; producer double-store (sc0 local-L2
//    + sc0sc1 MALL); consumer sc0-first loads escalating to sc0sc1.
//  - 448 workers: 128x256 GEMM tiles in t-order, bf16 xzT sc0sc1 + ready[].
// ---------------------------------------------------------------------------
__global__ __launch_bounds__(512, 4) void lstm_mega(
    const float* __restrict__ x, const float* __restrict__ W,
    const float* __restrict__ bias, const float* __restrict__ U,
    short* __restrict__ xzT, uint32_t* __restrict__ h0buf,
    uint32_t* __restrict__ h1buf, int* __restrict__ ready,
    int* __restrict__ claim, float* __restrict__ out)
{
  extern __shared__ char smem[];
  const int tid  = threadIdx.x;
  const int lane = tid & 63, wave = tid >> 6;
  const int fr = lane & 15, kg = lane >> 4;

  // ---- role claim (phase 1: XCD0-affine) ----
  int* role_sh = (int*)smem;
  if (tid == 0) {
    int xcd = 0;
    asm volatile("s_getreg_b32 %0, hwreg(HW_REG_XCC_ID)" : "=s"(xcd));
    int r = -1;
    if ((xcd & 7) == 0)
      r = __hip_atomic_fetch_add(claim, 1, __ATOMIC_RELAXED, __HIP_MEMORY_SCOPE_AGENT);
    role_sh[0] = r;
  }
  __syncthreads();
  int role = role_sh[0];
  __syncthreads();   // smem reused below

  if (role < 0 || role >= NROLE) {
    // ================= GEMM worker: 128x256 tiles =================
    short* As = (short*)smem;             // [128][32]  8 KB
    short* Bs = (short*)(smem + 8192);    // [32][256] 16 KB
    short* Cs = (short*)smem;             // [128][264] reused after k-loop
    const int wm = (wave >> 2) * 64, wn = (wave & 3) * 64;
    const int fq = lane >> 4;
    int wid;
    if (tid == 0)
      role_sh[1] = __hip_atomic_fetch_add(claim + 4, 1, __ATOMIC_RELAXED,
                                          __HIP_MEMORY_SCOPE_AGENT);
    __syncthreads();
    wid = role_sh[1];
    __syncthreads();

    for (int tile = wid; tile < 2048; tile += NWRK) {
      const int mtile = tile >> 4;         // 128 m-rows = 2 t x 64 b
      const int bn = (tile & 15) * 256;    // one gate, 16 rb
      f32x4 acc[4][4] = {};

      for (int k0 = 0; k0 < D_; k0 += 32) {
        {  // stage A: 128 rows; m = mtile*128+r ; x row = (m&63)*256 + (m>>6)
          const int r0 = tid >> 3, kq = (tid & 7) * 4;
          #pragma unroll
          for (int it = 0; it < 2; ++it) {
            const int r = r0 + it * 64;
            const int m = mtile * 128 + r;
            const int xr = (m & 63) * 256 + (m >> 6);
            const float4 v = *reinterpret_cast<const float4*>(&x[(size_t)xr * D_ + k0 + kq]);
            short4v s; s.x = f2bs(v.x); s.y = f2bs(v.y); s.z = f2bs(v.z); s.w = f2bs(v.w);
            *reinterpret_cast<short4v*>(&As[r * 32 + kq]) = s;
          }
        }
        {  // stage B: 32 k-rows x 256 n
          const int kr0 = tid >> 6, nq = (tid & 63) * 4;
          #pragma unroll
          for (int it = 0; it < 4; ++it) {
            const int krow = kr0 + it * 8;
            const float4 v = *reinterpret_cast<const float4*>(&W[(size_t)(k0 + krow) * NG + bn + nq]);
            short4v s; s.x = f2bs(v.x); s.y = f2bs(v.y); s.z = f2bs(v.z); s.w = f2bs(v.w);
            *reinterpret_cast<short4v*>(&Bs[krow * 256 + nq]) = s;
          }
        }
        __syncthreads();

        short8 af[4];
        #pragma unroll
        for (int mi = 0; mi < 4; ++mi)
          af[mi] = *reinterpret_cast<const short8*>(&As[(wm + mi * 16 + fr) * 32 + kg * 8]);
        #pragma unroll
        for (int ni = 0; ni < 4; ++ni) {
          short8 bf;
          #pragma unroll
          for (int j = 0; j < 8; ++j) bf[j] = Bs[(kg * 8 + j) * 256 + wn + ni * 16 + fr];
          #pragma unroll
          for (int mi = 0; mi < 4; ++mi)
            acc[mi][ni] = __builtin_amdgcn_mfma_f32_16x16x32_bf16(af[mi], bf, acc[mi][ni], 0, 0, 0);
        }
        __syncthreads();
      }

      // epilogue via LDS C-tile, then coalesced sc0sc1 scatter
      const int g = bn >> 10, rb0 = (bn & 1023) >> 4;
      __syncthreads();
      #pragma unroll
      for (int ni = 0; ni < 4; ++ni) {
        const int col = wn + ni * 16 + fr;
        const float bv = bias[bn + col];
        #pragma unroll
        for (int mi = 0; mi < 4; ++mi) {
          const int rowl = wm + mi * 16 + (lane >> 4) * 4;
          #pragma unroll
          for (int r = 0; r < 4; ++r)
            Cs[(rowl + r) * 264 + col] = f2bs(acc[mi][ni][r] + bv);
        }
      }
      __syncthreads();
      #pragma unroll
      for (int it = 0; it < 4; ++it) {
        const int cid = it * 512 + tid;            // 0..2047
        const int rl = cid >> 4, rbi = cid & 15;
        const int t = mtile * 2 + (rl >> 6);
        const int b = rl & 63;
        short* dst = xzT + ((size_t)((rb0 + rbi) * 256 + t) * 64 + b) * 64 + g * 16;
        const int4v v0 = *reinterpret_cast<const int4v*>(&Cs[rl * 264 + rbi * 16]);
        const int4v v1 = *reinterpret_cast<const int4v*>(&Cs[rl * 264 + rbi * 16 + 8]);
        asm volatile("global_store_dwordx4 %0, %1, off sc0 sc1\n\t"
                     "global_store_dwordx4 %0, %2, off offset:16 sc0 sc1"
                     :: "v"(dst), "v"(v0), "v"(v1) : "memory");
      }
      asm volatile("s_waitcnt vmcnt(0)" ::: "memory");
      __syncthreads();
      if (tid == 0)
        __hip_atomic_fetch_add(&ready[mtile >> 1], 1, __ATOMIC_RELAXED,
                               __HIP_MEMORY_SCOPE_AGENT);
      __syncthreads();
    }

    // rescue any unclaimed recurrence role (hang-free guarantee)
    if (tid == 0)
      role_sh[0] = __hip_atomic_fetch_add(claim, 1, __ATOMIC_RELAXED,
                                          __HIP_MEMORY_SCOPE_AGENT);
    __syncthreads();
    role = role_sh[0];
    __syncthreads();
    if (role < 0 || role >= NROLE) return;
    // falls through to recurrence with claimed role
  }

  // ================= recurrence (single-XCD L2-local comm) =================
  char*  Us  = smem;                          // i8 [ks][kg][col][j] 64 KB
  float* zsm = (float*)(smem + 65536);        // [64 b][64 c] f32 16 KB

  const int u0 = role * 16;
  const int mt = wave & 3;        // batch tile (16 rows)
  const int kh = wave >> 2;       // K half
  const int gb = tid >> 3, gup = tid & 7;

  // per-column scales (cols c = g*16+uj): zsm[c]=s, zsm[64+c]=127/s
  if (tid < 64) {
    float m = 1e-30f;
    for (int k = 0; k < 1024; ++k)
      m = fmaxf(m, fabsf(U[(size_t)k * NG + (tid >> 4) * NH + u0 + (tid & 15)]));
    zsm[tid] = m;
    zsm[64 + tid] = 127.f / m;
  }
  __syncthreads();
  // quantize U slice into LDS i8, fragment-packed [ks][kg][col][j]
  for (int idx = tid; idx < 1024 * 64; idx += 512) {
    const int k = idx >> 6, c = idx & 63;
    const float v = U[(size_t)k * NG + (c >> 4) * NH + u0 + (c & 15)];
    const int q = (int)rintf(v * zsm[64 + c]);
    Us[(((k >> 5) * 4 + ((k >> 3) & 3)) * 64 + c) * 8 + (k & 7)] = (char)q;
  }
  // per-lane z scales for MFMA cols nt*16+fr
  float sdiv[4];
  #pragma unroll
  for (int nt = 0; nt < 4; ++nt) sdiv[nt] = zsm[nt * 16 + fr] * (1.f / 16129.f);
  __syncthreads();

  float creg0 = 0.f, creg1 = 0.f;
  // consumer byte offset: word ((ks*4+kg)*64 + row)*4, row = mt*16+fr
  const int voff0 = kh * 65536 + kg * 1024 + (mt * 16 + fr) * 16;
  // producer word index for units u = u0+2*gup (+1): one u32 (tag|2xi8)
  const int uu = u0 + 2 * gup;
  const int pidx = (((uu >> 5) * 4 + ((uu >> 3) & 3)) * 64 + gb) * 4 + ((uu >> 1) & 3);
  uint64_t rt0 = rtclock();
  int grpOK = -1;

  for (int t = 0; t < T_; ++t) {
    const uint32_t* __restrict__ hpv = (t & 1) ? h0buf : h1buf;  // h(t-1)
    uint32_t* __restrict__ hnx       = (t & 1) ? h1buf : h0buf;  // h(t)

    // xz availability gate (one dwordx4 per 16 steps; >= handles duplicates)
    const int grp = t >> 4;
    if (grp > grpOK) {
      if (lane == 0) {
        int spun = 0;
        for (;;) {
          int4v rv;
          asm volatile("global_load_dwordx4 %0, %1, off sc0 sc1\n\t"
                       "s_waitcnt vmcnt(0)"
                       : "=&v"(rv) : "v"(ready + grp * 4) : "memory");
          if (rv[0] >= 32 && rv[1] >= 32 && rv[2] >= 32 && rv[3] >= 32) break;
          spun = 1;
          __builtin_amdgcn_s_sleep(16);
        }
        if (spun) {
          #pragma unroll
          for (int s = 0; s < 4; ++s) __builtin_amdgcn_s_sleep(127);
        }
      }
      grpOK = grp;
    }

    int xzw[4];
    {
      const short* xb = xzT + ((((size_t)role * 256 + t) * 64 + gb) * 64 + 2 * gup);
      asm volatile("global_load_dword %0, %4, off sc0 sc1\n\t"
                   "global_load_dword %1, %4, off offset:32 sc0 sc1\n\t"
                   "global_load_dword %2, %4, off offset:64 sc0 sc1\n\t"
                   "global_load_dword %3, %4, off offset:96 sc0 sc1"
                   : "=&v"(xzw[0]), "=&v"(xzw[1]), "=&v"(xzw[2]), "=&v"(xzw[3])
                   : "v"(xb) : "memory");
    }

    int4v acc[4] = {};
    if (t > 0) {
      const uint32_t tgw = (uint32_t)t << 16;
      int4v bufA[8], bufB[8];
      while ((uint64_t)(rtclock() - rt0) < DLY_TICKS)
        __builtin_amdgcn_s_sleep(1);
      ISSUE_F(bufA, 0); ISSUE_F(bufB, 32768);
      WAITV(8);                      // xz + A landed (B in flight)
      {
        int tries = 0;
        for (;;) {
          uint32_t bad = 0; CHECKBUF(bufA);
          if (__all(bad == 0)) break;
          __builtin_amdgcn_s_sleep(2);
          if (++tries < 6) { ISSUE_F(bufA, 0); } else { ISSUE_S(bufA, 0); }
          WAITV(0);
        }
      }
      MFMA_SUB(bufA, 0);
      WAITV(0);
      {
        int tries = 0;
        for (;;) {
          uint32_t bad = 0; CHECKBUF(bufB);
          if (__all(bad == 0)) break;
          __builtin_amdgcn_s_sleep(2);
          if (++tries < 6) { ISSUE_F(bufB, 32768); } else { ISSUE_S(bufB, 32768); }
          WAITV(0);
        }
      }
      MFMA_SUB(bufB, 8);

      if (kh == 1) {
        #pragma unroll
        for (int nt = 0; nt < 4; ++nt)
          #pragma unroll
          for (int r = 0; r < 4; ++r)
            zsm[(mt * 16 + kg * 4 + r) * 64 + nt * 16 + fr] = (float)acc[nt][r] * sdiv[nt];
      }
      __syncthreads();   // S1
      if (kh == 0) {
        #pragma unroll
        for (int nt = 0; nt < 4; ++nt)
          #pragma unroll
          for (int r = 0; r < 4; ++r)
            zsm[(mt * 16 + kg * 4 + r) * 64 + nt * 16 + fr] += (float)acc[nt][r] * sdiv[nt];
      }
      __syncthreads();   // S2
    } else {
      asm volatile("s_waitcnt vmcnt(0)" ::: "memory");
    }

    {  // gate math: b = gb, units u0+2*gup, u0+2*gup+1
      float z[4][2];
      #pragma unroll
      for (int g = 0; g < 4; ++g) {
        z[g][0] = bs2f((short)(xzw[g] & 0xFFFF));
        z[g][1] = bs2f((short)(((uint32_t)xzw[g]) >> 16));
        if (t > 0) {
          const float2 zz = *reinterpret_cast<const float2*>(&zsm[gb * 64 + g * 16 + 2 * gup]);
          z[g][0] += zz.x; z[g][1] += zz.y;
        }
      }
      float hh0, hh1;
      {
        const float ig = fsigm(z[0][0]), fg = fsigm(z[1][0]);
        const float gg = ftanh(z[2][0]), og = fsigm(z[3][0]);
        creg0 = fg * creg0 + ig * gg;  hh0 = og * ftanh(creg0);
      }
      {
        const float ig = fsigm(z[0][1]), fg = fsigm(z[1][1]);
        const float gg = ftanh(z[2][1]), og = fsigm(z[3][1]);
        creg1 = fg * creg1 + ig * gg;  hh1 = og * ftanh(creg1);
      }
      if (t < T_ - 1) {
        const int q0 = (int)rintf(hh0 * 127.f);
        const int q1 = (int)rintf(hh1 * 127.f);
        const uint32_t word = ((uint32_t)(t + 1) << 16) |
                              (((uint32_t)q1 & 0xFF) << 8) | ((uint32_t)q0 & 0xFF);
        uint32_t* hp32 = hnx + pidx;
        // double store: local-L2 fast path + MALL write-through (idempotent)
        asm volatile("global_store_dword %0, %1, off sc0\n\t"
                     "global_store_dword %0, %1, off sc0 sc1"
                     :: "v"(hp32), "v"(word) : "memory");
      }
      rt0 = rtclock();
      float2 o; o.x = hh0; o.y = hh1;
      *reinterpret_cast<float2*>(&out[((size_t)gb * T_ + t) * NH + u0 + 2 * gup]) = o;
    }
    __builtin_amdgcn_s_barrier();
  }
}

extern "C" void kernel_launch(void* const* d_in, const int* in_sizes, int n_in,
                              void* d_out, int out_size, void* d_ws, size_t ws_size,
                              hipStream_t stream) {
  const float* x    = (const float*)d_in[0];
  const float* W    = (const float*)d_in[1];
  const float* U    = (const float*)d_in[2];
  const float* bias = (const float*)d_in[3];
  float* out = (float*)d_out;
  char* ws = (char*)d_ws;

  // ws: xzT bf16 128 MiB | h ping/pong (tag|2xi8 words) 2x128 KiB
  //     | ready 4 KiB | claim 64 B
  short*    xzT   = (short*)ws;
  uint32_t* hA    = (uint32_t*)(ws + 134217728);
  uint32_t* hB    = (uint32_t*)(ws + 134217728 + 131072);
  int*      ready = (int*)(ws + 134217728 + 262144);
  int*      claim = (int*)(ws + 134217728 + 262144 + 4096);

  // zero h tags + ready + claim each launch (graph replays re-run this)
  hipMemsetAsync(ws + 134217728, 0, 262144 + 4096 + 64, stream);

  hipFuncSetAttribute((const void*)lstm_mega,
                      hipFuncAttributeMaxDynamicSharedMemorySize, LDS_BYTES);
  lstm_mega<<<dim3(512), dim3(512), LDS_BYTES, stream>>>(
      x, W, bias, U, xzT, hA, hB, ready, claim, out);
}

// Round 17
// 1898.329 us; speedup vs baseline: 3.3217x; 3.3217x over previous
//
#include <hip/hip_runtime.h>
#include <cstdint>
#include <cstddef>

typedef __attribute__((ext_vector_type(8))) short short8;
typedef __attribute__((ext_vector_type(4))) short short4v;
typedef __attribute__((ext_vector_type(4))) float f32x4;
typedef __attribute__((ext_vector_type(4))) int int4v;

static constexpr int B_ = 64, T_ = 256, D_ = 1024, NH = 1024, NG = 4096;
static constexpr int NBLK = 64;          // recurrence blocks
static constexpr int NWRK = 96;          // gemm worker blocks (r16: 192 -> 96)
// LDS: recurrence Us 128K + zsm [64][68] f32 = 148480; gemm path uses < that
static constexpr int LDS_BYTES = 131072 + 64 * 68 * 4;
static constexpr uint64_t DLY_TICKS = 50;  // 0.5 us @ 100MHz s_memrealtime

__device__ __forceinline__ short f2bs(float f) {
  union { float f; uint32_t u; } cv; cv.f = f;
  uint32_t u = cv.u;
  uint32_t r = (u + 0x7fffu + ((u >> 16) & 1u)) >> 16;  // RNE
  return (short)(uint16_t)r;
}
__device__ __forceinline__ float bs2f(short s) {
  union { uint32_t u; float f; } cv; cv.u = ((uint32_t)(uint16_t)s) << 16; return cv.f;
}
__device__ __forceinline__ float fsigm(float x) {
  return __builtin_amdgcn_rcpf(1.f + __expf(-x));
}
__device__ __forceinline__ float ftanh(float x) {
  return 1.f - 2.f * __builtin_amdgcn_rcpf(__expf(2.f * x) + 1.f);
}
__device__ __forceinline__ uint64_t rtclock() {
  uint64_t v;
  asm volatile("s_memrealtime %0\n\ts_waitcnt lgkmcnt(0)" : "=s"(v));
  return v;
}

#define WAITV(N) do { asm volatile("s_waitcnt vmcnt(" #N ")" ::: "memory"); \
                      __builtin_amdgcn_sched_barrier(0); } while (0)

#define HL2(B0, B1, VO) \
  asm volatile("global_load_dwordx4 %0, %2, %3 sc0 sc1\n\t" \
               "global_load_dwordx4 %1, %2, %3 offset:16 sc0 sc1" \
               : "=&v"(B0), "=&v"(B1) : "v"(VO), "s"(hpv) : "memory")

#define ISSUE_A { _Pragma("unroll") \
  for (int K = 0; K < 8; ++K) HL2(bufA[2*K], bufA[2*K+1], voff0 + K * 8192); }
#define ISSUE_B { _Pragma("unroll") \
  for (int K = 0; K < 8; ++K) HL2(bufB[2*K], bufB[2*K+1], voff0 + 65536 + K * 8192); }

#define CHECKBUF(BUF) { _Pragma("unroll") \
  for (int i = 0; i < 16; ++i) { \
    bad |= ((uint32_t)BUF[i][0] ^ tgw); bad |= ((uint32_t)BUF[i][1] ^ tgw); \
    bad |= ((uint32_t)BUF[i][2] ^ tgw); bad |= ((uint32_t)BUF[i][3] ^ tgw); \
  } bad &= 0xFFFF0000u; }

#define MFMA_SUB(BUF, KB) { _Pragma("unroll") \
  for (int K = 0; K < 8; ++K) { \
    int4v pk; \
    pk[0] = (BUF[2*K][0]   & 0xFFFF) | (BUF[2*K][1]   << 16); \
    pk[1] = (BUF[2*K][2]   & 0xFFFF) | (BUF[2*K][3]   << 16); \
    pk[2] = (BUF[2*K+1][0] & 0xFFFF) | (BUF[2*K+1][1] << 16); \
    pk[3] = (BUF[2*K+1][2] & 0xFFFF) | (BUF[2*K+1][3] << 16); \
    const short8 fa = __builtin_bit_cast(short8, pk); \
    const int ksAbs = kh * 16 + (KB) + K; \
    _Pragma("unroll") \
    for (int nt = 0; nt < 4; ++nt) { \
      const short8 fb = *reinterpret_cast<const short8*>(&Us[((ksAbs*4 + kg)*64 + nt*16 + fr)*8]); \
      acc[nt] = __builtin_amdgcn_mfma_f32_16x16x32_bf16(fa, fb, acc[nt], 0, 0, 0); \
    } \
  } }

// ---------------------------------------------------------------------------
// FUSED kernel (r14 champion, one knob turned: NWRK 192 -> 96):
// blocks [0,64) = persistent recurrence; blocks [64,160) = persistent GEMM
// workers producing xzT in t-order. Halving the worker count halves the
// instantaneous MALL staging pressure (queueing delay is superlinear near
// saturation) while production still outruns consumption:
//   per ~65us round, 96 workers produce 6 t-groups (24 steps' xz) vs 150us
//   to consume them; first-chunk wait unchanged (tiles 0-63 in round 0).
// ---------------------------------------------------------------------------
__global__ __launch_bounds__(512, 1) void lstm_fused(
    const float* __restrict__ x, const float* __restrict__ W,
    const float* __restrict__ bias, const float* __restrict__ U,
    short* __restrict__ xzT, uint32_t* __restrict__ h0buf,
    uint32_t* __restrict__ h1buf, int* __restrict__ ready,
    float* __restrict__ out)
{
  extern __shared__ char smem[];
  const int tid  = threadIdx.x;
  const int lane = tid & 63, wave = tid >> 6;
  const int bid  = blockIdx.x;
  const int fr = lane & 15, kg = lane >> 4;

  if (bid >= NBLK) {
    // ================= GEMM worker =================
    short* As = (short*)smem;             // [256][32]
    short* Bs = (short*)(smem + 16384);   // [32][256]
    short* Cs = (short*)smem;             // [128][264] (reused after k-loop)
    const int wm = (wave >> 2) * 128, wn = (wave & 3) * 64;
    const int fq = lane >> 4;
    const int wid = bid - NBLK;

    for (int tile = wid; tile < 1024; tile += NWRK) {
      const int tt = tile >> 4;            // t in [4tt, 4tt+4)
      const int bn = (tile & 15) * 256;    // one gate, 16 rb
      f32x4 acc[8][4] = {};

      for (int k0 = 0; k0 < D_; k0 += 32) {
        {  // stage A: tile row r -> x row (m&63)*256 + (m>>6), m = tt*256+r
          const int r0 = tid >> 3, kq = (tid & 7) * 4;
          #pragma unroll
          for (int it = 0; it < 4; ++it) {
            const int r = r0 + it * 64;
            const int m = tt * 256 + r;
            const int xr = (m & 63) * 256 + (m >> 6);
            const float4 v = *reinterpret_cast<const float4*>(&x[(size_t)xr * D_ + k0 + kq]);
            short4v s; s.x = f2bs(v.x); s.y = f2bs(v.y); s.z = f2bs(v.z); s.w = f2bs(v.w);
            *reinterpret_cast<short4v*>(&As[r * 32 + kq]) = s;
          }
        }
        {  // stage B
          const int kr0 = tid >> 6, nq = (tid & 63) * 4;
          #pragma unroll
          for (int it = 0; it < 4; ++it) {
            const int krow = kr0 + it * 8;
            const float4 v = *reinterpret_cast<const float4*>(&W[(size_t)(k0 + krow) * NG + bn + nq]);
            short4v s; s.x = f2bs(v.x); s.y = f2bs(v.y); s.z = f2bs(v.z); s.w = f2bs(v.w);
            *reinterpret_cast<short4v*>(&Bs[krow * 256 + nq]) = s;
          }
        }
        __syncthreads();

        short8 af[8];
        #pragma unroll
        for (int mi = 0; mi < 8; ++mi)
          af[mi] = *reinterpret_cast<const short8*>(&As[(wm + mi * 16 + fr) * 32 + kg * 8]);
        #pragma unroll
        for (int ni = 0; ni < 4; ++ni) {
          short8 bf;
          #pragma unroll
          for (int j = 0; j < 8; ++j) bf[j] = Bs[(kg * 8 + j) * 256 + wn + ni * 16 + fr];
          #pragma unroll
          for (int mi = 0; mi < 8; ++mi)
            acc[mi][ni] = __builtin_amdgcn_mfma_f32_16x16x32_bf16(af[mi], bf, acc[mi][ni], 0, 0, 0);
        }
        __syncthreads();
      }

      // epilogue: two 128-row half passes through Cs; sc0sc1 scatter stores
      const int g = bn >> 10, rb0 = (bn & 1023) >> 4;
      #pragma unroll
      for (int hp = 0; hp < 2; ++hp) {
        __syncthreads();
        if ((wave >> 2) == hp) {
          #pragma unroll
          for (int ni = 0; ni < 4; ++ni) {
            const int col = wn + ni * 16 + fr;
            const float bv = bias[bn + col];
            #pragma unroll
            for (int mi = 0; mi < 8; ++mi) {
              const int rowl = mi * 16 + fq * 4;
              #pragma unroll
              for (int r = 0; r < 4; ++r)
                Cs[(rowl + r) * 264 + col] = f2bs(acc[mi][ni][r] + bv);
            }
          }
        }
        __syncthreads();
        #pragma unroll
        for (int it = 0; it < 4; ++it) {
          const int cid = it * 512 + tid;          // 0..2047
          const int tl = cid >> 4, rbi = cid & 15;
          const int r = hp * 128 + tl;
          const int t = tt * 4 + (r >> 6);
          const int b = r & 63;
          short* dst = xzT + ((size_t)((rb0 + rbi) * 256 + t) * 64 + b) * 64 + g * 16;
          const int4v v0 = *reinterpret_cast<const int4v*>(&Cs[tl * 264 + rbi * 16]);
          const int4v v1 = *reinterpret_cast<const int4v*>(&Cs[tl * 264 + rbi * 16 + 8]);
          asm volatile("global_store_dwordx4 %0, %1, off sc0 sc1\n\t"
                       "global_store_dwordx4 %0, %2, off offset:16 sc0 sc1"
                       :: "v"(dst), "v"(v0), "v"(v1) : "memory");
        }
      }
      asm volatile("s_waitcnt vmcnt(0)" ::: "memory");
      __syncthreads();
      if (tid == 0)
        __hip_atomic_fetch_add(&ready[tt], 1, __ATOMIC_RELAXED, __HIP_MEMORY_SCOPE_AGENT);
    }
    return;
  }

  // ================= recurrence (r11 champion + ready gate + sc xz loads) ==
  short* Us  = (short*)smem;                   // [k>>3][c][k&7], 128 KiB
  float* zsm = (float*)(smem + 131072);        // [64 b][68], padded

  const int u0 = bid * 16;
  const int mt = wave & 3;        // batch tile (16 rows)
  const int kh = wave >> 2;       // K half
  const int gb = tid >> 3, gup = tid & 7;  // gate-math: b, unit-pair

  for (int idx = tid; idx < 1024 * 64; idx += 512) {
    const int k = idx >> 6, c = idx & 63;
    Us[((k >> 3) * 64 + c) * 8 + (k & 7)] =
        f2bs(U[(size_t)k * NG + (c >> 4) * NH + u0 + (c & 15)]);
  }
  float creg0 = 0.f, creg1 = 0.f;
  const int voff0 = kh * 131072 + kg * 2048 + mt * 512 + fr * 32;
  const int pks = bid >> 1;
  const int pkg = ((bid & 1) << 1) + (gup >> 2);
  const int pj  = (2 * gup) & 7;
  const int pidx = ((pks * 4 + pkg) * 64 + gb) * 8 + pj;
  __syncthreads();
  uint64_t rt0 = rtclock();
  int grpOK = -1;   // highest 16-step group known fully produced

  for (int t = 0; t < T_; ++t) {
    const uint32_t* __restrict__ hpv = (t & 1) ? h0buf : h1buf;  // h(t-1)
    uint32_t* __restrict__ hnx       = (t & 1) ? h1buf : h0buf;  // h(t)

    // Gate on xz availability: one dwordx4 poll per 16 steps (steady: free).
    const int grp = t >> 4;
    if (grp > grpOK) {
      if (lane == 0) {
        int spun = 0;
        for (;;) {
          int4v rv;
          asm volatile("global_load_dwordx4 %0, %1, off sc0 sc1\n\t"
                       "s_waitcnt vmcnt(0)"
                       : "=&v"(rv) : "v"(ready + grp * 4) : "memory");
          if (rv[0] == 16 && rv[1] == 16 && rv[2] == 16 && rv[3] == 16) break;
          spun = 1;
          __builtin_amdgcn_s_sleep(16);
        }
        if (spun) {  // settle: cover store->visible lag of freshest tiles
          #pragma unroll
          for (int s = 0; s < 4; ++s) __builtin_amdgcn_s_sleep(127);
        }
      }
      grpOK = grp;
    }

    int xzw[4];
    {
      const short* xb = xzT + ((((size_t)bid * 256 + t) * 64 + gb) * 64 + 2 * gup);
      asm volatile("global_load_dword %0, %4, off sc0 sc1\n\t"
                   "global_load_dword %1, %4, off offset:32 sc0 sc1\n\t"
                   "global_load_dword %2, %4, off offset:64 sc0 sc1\n\t"
                   "global_load_dword %3, %4, off offset:96 sc0 sc1"
                   : "=&v"(xzw[0]), "=&v"(xzw[1]), "=&v"(xzw[2]), "=&v"(xzw[3])
                   : "v"(xb) : "memory");
    }

    f32x4 acc[4] = {};
    if (t > 0) {
      const uint32_t tgw = (uint32_t)t << 16;  // expected tag for h(t-1)
      int4v bufA[16], bufB[16];
      while ((uint64_t)(rtclock() - rt0) < DLY_TICKS)
        __builtin_amdgcn_s_sleep(1);
      ISSUE_A; ISSUE_B;
      WAITV(16);            // xz + A landed (B in flight)
      for (;;) {
        uint32_t bad = 0; CHECKBUF(bufA);
        if (__all(bad == 0)) break;
        __builtin_amdgcn_s_sleep(4);
        ISSUE_A; WAITV(0);
      }
      MFMA_SUB(bufA, 0);
      WAITV(0);
      for (;;) {
        uint32_t bad = 0; CHECKBUF(bufB);
        if (__all(bad == 0)) break;
        __builtin_amdgcn_s_sleep(4);
        ISSUE_B; WAITV(0);
      }
      MFMA_SUB(bufB, 8);

      if (kh == 1) {
        #pragma unroll
        for (int nt = 0; nt < 4; ++nt)
          #pragma unroll
          for (int r = 0; r < 4; ++r)
            zsm[(mt * 16 + kg * 4 + r) * 68 + nt * 16 + fr] = acc[nt][r];
      }
      __syncthreads();   // S1
      if (kh == 0) {
        #pragma unroll
        for (int nt = 0; nt < 4; ++nt)
          #pragma unroll
          for (int r = 0; r < 4; ++r)
            zsm[(mt * 16 + kg * 4 + r) * 68 + nt * 16 + fr] += acc[nt][r];
      }
      __syncthreads();   // S2
    } else {
      asm volatile("s_waitcnt vmcnt(0)" ::: "memory");  // xzw landed
    }

    {  // gate math: b = gb, units u0+2*gup, u0+2*gup+1
      float z[4][2];
      #pragma unroll
      for (int g = 0; g < 4; ++g) {
        z[g][0] = bs2f((short)(xzw[g] & 0xFFFF));
        z[g][1] = bs2f((short)(((uint32_t)xzw[g]) >> 16));
        if (t > 0) {
          const float2 zz = *reinterpret_cast<const float2*>(&zsm[gb * 68 + g * 16 + 2 * gup]);
          z[g][0] += zz.x; z[g][1] += zz.y;
        }
      }
      float hh0, hh1;
      {
        const float ig = fsigm(z[0][0]), fg = fsigm(z[1][0]);
        const float gg = ftanh(z[2][0]), og = fsigm(z[3][0]);
        creg0 = fg * creg0 + ig * gg;  hh0 = og * ftanh(creg0);
      }
      {
        const float ig = fsigm(z[0][1]), fg = fsigm(z[1][1]);
        const float gg = ftanh(z[2][1]), og = fsigm(z[3][1]);
        creg1 = fg * creg1 + ig * gg;  hh1 = og * ftanh(creg1);
      }
      if (t < T_ - 1) {
        const uint32_t tgp = (uint32_t)(t + 1) << 16;
        const uint64_t hw64 =
            (uint64_t)(tgp | (uint32_t)(uint16_t)f2bs(hh0)) |
            ((uint64_t)(tgp | (uint32_t)(uint16_t)f2bs(hh1)) << 32);
        (void)__hip_atomic_exchange((uint64_t*)(hnx + pidx), hw64,
                                    __ATOMIC_RELAXED, __HIP_MEMORY_SCOPE_AGENT);
      }
      rt0 = rtclock();
      float2 o; o.x = hh0; o.y = hh1;
      *reinterpret_cast<float2*>(&out[((size_t)gb * T_ + t) * NH + u0 + 2 * gup]) = o;
    }
    __builtin_amdgcn_s_barrier();
  }
}

extern "C" void kernel_launch(void* const* d_in, const int* in_sizes, int n_in,
                              void* d_out, int out_size, void* d_ws, size_t ws_size,
                              hipStream_t stream) {
  const float* x    = (const float*)d_in[0];
  const float* W    = (const float*)d_in[1];
  const float* U    = (const float*)d_in[2];
  const float* bias = (const float*)d_in[3];
  float* out = (float*)d_out;
  char* ws = (char*)d_ws;

  // ws: xzT bf16 128 MiB | h ping/pong 2 x 256 KiB | ready 64 ints
  short*    xzT   = (short*)ws;
  uint32_t* hA    = (uint32_t*)(ws + 134217728);
  uint32_t* hB    = (uint32_t*)(ws + 134217728 + 262144);
  int*      ready = (int*)(ws + 134217728 + 524288);

  // Zero h tags + ready counters each launch (graph replays re-run this).
  hipMemsetAsync(ws + 134217728, 0, 524288 + 4096, stream);

  hipFuncSetAttribute((const void*)lstm_fused,
                      hipFuncAttributeMaxDynamicSharedMemorySize, LDS_BYTES);
  lstm_fused<<<dim3(NBLK + NWRK), dim3(512), LDS_BYTES, stream>>>(
      x, W, bias, U, xzT, hA, hB, ready, out);
}